// Round 3
// baseline (26.322 us; speedup 1.0000x reference)
//
#include <hip/hip_runtime.h>

// SparseIF: multi-step integrate-and-fire, soft reset (v_reset=None), th=1.0
//   v += c[t]; spike = (v >= 1) ? 1 : 0; v -= spike;  out[t] = spike
// Shapes: current [T=64, B=32, D=8192] f32, out same. Pure streaming:
// 64 MB in + 64 MB out => HBM roofline ~20.3 us @ 6.3 TB/s achievable.
//
// R1: float4, 65536 threads (1 wave/SIMD) -> 24.15 us (5.56 TB/s, 88%).
// R2: occupancy theory -> float2 + nontemporal; compile fail (builtin rejects
//     HIP_vector_type). R3: same plan with clang ext_vector_type(2) float.

#define T_STEPS 64
#define N_NEUR  (32 * 8192)      // B*D = 262144
#define VEC     2
#define NV      (N_NEUR / VEC)   // 131072 2-wide columns

typedef float v2f __attribute__((ext_vector_type(2)));

__global__ __launch_bounds__(256)
void sparse_if_kernel(const v2f* __restrict__ in, v2f* __restrict__ out) {
    const int tid = blockIdx.x * blockDim.x + threadIdx.x;  // 0..NV-1
    // Column tid of the [T][NV] v2f matrix; stride NV between timesteps.
    float vx = 0.f, vy = 0.f;

#pragma unroll
    for (int t = 0; t < T_STEPS; ++t) {
        const int idx = tid + t * NV;           // < 64*131072 = 2^23, fits int
        v2f c = __builtin_nontemporal_load(&in[idx]);

        vx += c.x;
        vy += c.y;

        const float sx = (vx >= 1.0f) ? 1.0f : 0.0f;
        const float sy = (vy >= 1.0f) ? 1.0f : 0.0f;

        vx -= sx;   // soft reset (th = 1.0)
        vy -= sy;

        v2f s;
        s.x = sx;
        s.y = sy;
        __builtin_nontemporal_store(s, &out[idx]);
    }
}

extern "C" void kernel_launch(void* const* d_in, const int* in_sizes, int n_in,
                              void* d_out, int out_size, void* d_ws, size_t ws_size,
                              hipStream_t stream) {
    const v2f* in  = reinterpret_cast<const v2f*>(d_in[0]);
    v2f*       out = reinterpret_cast<v2f*>(d_out);

    const int threads = 256;
    const int blocks  = NV / threads;  // 512 blocks -> 2 per CU, 8 waves/CU
    sparse_if_kernel<<<blocks, threads, 0, stream>>>(in, out);
}

// Round 4
// 23.933 us; speedup vs baseline: 1.0998x; 1.0998x over previous
//
#include <hip/hip_runtime.h>

// SparseIF: multi-step integrate-and-fire, soft reset (v_reset=None), th=1.0
//   v += c[t]; spike = (v >= 1) ? 1 : 0; v -= spike;  out[t] = spike
// Shapes: current [T=64, B=32, D=8192] f32, out same. Streaming, 128 MB total;
// both buffers fit in 256 MB L3 -> steady-state replays can be L3-resident.
//
// R1: float4, 1024 waves (1/SIMD), plain ld/st          -> 24.15 us
// R3: float2 + nontemporal (bypasses L2/L3!)            -> 26.32 us (regress)
// R4: float2, plain ld/st — isolate the occupancy lever (2 waves/SIMD),
//     keep L3 in play.

#define T_STEPS 64
#define N_NEUR  (32 * 8192)      // B*D = 262144
#define VEC     2
#define NV      (N_NEUR / VEC)   // 131072 2-wide columns

typedef float v2f __attribute__((ext_vector_type(2)));

__global__ __launch_bounds__(256)
void sparse_if_kernel(const v2f* __restrict__ in, v2f* __restrict__ out) {
    const int tid = blockIdx.x * blockDim.x + threadIdx.x;  // 0..NV-1
    // Column tid of the [T][NV] v2f matrix; stride NV between timesteps.
    float vx = 0.f, vy = 0.f;

#pragma unroll
    for (int t = 0; t < T_STEPS; ++t) {
        const int idx = tid + t * NV;           // < 2^23, fits int
        v2f c = in[idx];

        vx += c.x;
        vy += c.y;

        const float sx = (vx >= 1.0f) ? 1.0f : 0.0f;
        const float sy = (vy >= 1.0f) ? 1.0f : 0.0f;

        vx -= sx;   // soft reset (th = 1.0)
        vy -= sy;

        v2f s;
        s.x = sx;
        s.y = sy;
        out[idx] = s;
    }
}

extern "C" void kernel_launch(void* const* d_in, const int* in_sizes, int n_in,
                              void* d_out, int out_size, void* d_ws, size_t ws_size,
                              hipStream_t stream) {
    const v2f* in  = reinterpret_cast<const v2f*>(d_in[0]);
    v2f*       out = reinterpret_cast<v2f*>(d_out);

    const int threads = 256;
    const int blocks  = NV / threads;  // 512 blocks -> 8 waves/CU (2/SIMD)
    sparse_if_kernel<<<blocks, threads, 0, stream>>>(in, out);
}